// Round 4
// baseline (332.438 us; speedup 1.0000x reference)
//
#include <hip/hip_runtime.h>
#include <math.h>

// ---------------- degree / norm ----------------

__global__ void deg_kernel(const int* __restrict__ col, int* __restrict__ deg, int E) {
    int e = blockIdx.x * blockDim.x + threadIdx.x;
    if (e < E) atomicAdd(&deg[col[e]], 1);
}

__global__ void dinv_kernel(const int* __restrict__ deg, float* __restrict__ dinv, int n) {
    int i = blockIdx.x * blockDim.x + threadIdx.x;
    if (i < n) dinv[i] = 1.0f / sqrtf((float)(deg[i] + 1));  // +1 self loop
}

// ---------------- 3-phase scan: deg -> rowptr/cursor ----------------
__global__ void scan_phase1(const int* __restrict__ deg, int* __restrict__ bsum, int n) {
    __shared__ int red[256];
    int tid = threadIdx.x;
    int base = blockIdx.x * 1024 + tid * 4;
    int s = 0;
    if (base + 3 < n) { int4 v = *(const int4*)&deg[base]; s = v.x + v.y + v.z + v.w; }
    else { for (int i = 0; i < 4; ++i) if (base + i < n) s += deg[base + i]; }
    red[tid] = s; __syncthreads();
    for (int off = 128; off > 0; off >>= 1) { if (tid < off) red[tid] += red[tid + off]; __syncthreads(); }
    if (tid == 0) bsum[blockIdx.x] = red[0];
}

__global__ void scan_phase2(const int* __restrict__ bsum, int* __restrict__ bpre,
                            int nb, int* __restrict__ rowptr, int n, int E) {
    int tid = threadIdx.x;  // 64 threads
    int sv = (tid < nb) ? bsum[tid] : 0;
    int v = sv;
    for (int off = 1; off < 64; off <<= 1) {
        int w = __shfl_up(v, off);
        if (tid >= off) v += w;
    }
    if (tid < nb) bpre[tid] = v - sv;   // exclusive
    if (tid == 0) rowptr[n] = E;
}

__global__ void scan_phase3(const int* __restrict__ deg, const int* __restrict__ bpre,
                            int* __restrict__ rowptr, int* __restrict__ cursor, int n) {
    __shared__ int tsum[256];
    int tid = threadIdx.x;
    int base = blockIdx.x * 1024 + tid * 4;
    int d[4] = {0, 0, 0, 0};
    if (base + 3 < n) { int4 v = *(const int4*)&deg[base]; d[0] = v.x; d[1] = v.y; d[2] = v.z; d[3] = v.w; }
    else { for (int i = 0; i < 4; ++i) if (base + i < n) d[i] = deg[base + i]; }
    int s = d[0] + d[1] + d[2] + d[3];
    tsum[tid] = s; __syncthreads();
    for (int off = 1; off < 256; off <<= 1) {
        int v = tsum[tid];
        int w = (tid >= off) ? tsum[tid - off] : 0;
        __syncthreads();
        tsum[tid] = v + w;
        __syncthreads();
    }
    int pre = bpre[blockIdx.x] + tsum[tid] - s;
    for (int i = 0; i < 4; ++i) {
        int idx = base + i;
        if (idx < n) { rowptr[idx] = pre; cursor[idx] = pre; pre += d[i]; }
    }
}

__global__ void fill_kernel(const int* __restrict__ row, const int* __restrict__ col,
                            int* __restrict__ cursor, int* __restrict__ csrc, int E) {
    int e = blockIdx.x * blockDim.x + threadIdx.x;
    if (e < E) {
        int c = col[e];
        int slot = atomicAdd(&cursor[c], 1);
        csrc[slot] = row[e];
    }
}

// ---------------- CSR gather aggregation + finalize ----------------
template<int F, bool OV>
__global__ void agg_finalize(const int* __restrict__ rowptr, const int* __restrict__ csrc,
                             const float* __restrict__ hs, const float* __restrict__ dinv,
                             const float* __restrict__ b, float* __restrict__ out,
                             int n, int ostride, int col0) {
    constexpr int L = F / 4;                 // lanes per node
    int tid = blockIdx.x * blockDim.x + threadIdx.x;
    int node = tid / L, lane = tid % L;
    if (node >= n) return;
    int f0 = lane * 4;
    int beg = rowptr[node], end = rowptr[node + 1];
    float4 sum = make_float4(0.f, 0.f, 0.f, 0.f);
    for (int j = beg; j < end; ++j) {
        int s = csrc[j];                     // uniform across the L-lane group
        float4 v = *(const float4*)&hs[(size_t)s * F + f0];
        sum.x += v.x; sum.y += v.y; sum.z += v.z; sum.w += v.w;
    }
    float4 self = *(const float4*)&hs[(size_t)node * F + f0];
    float di = dinv[node];
    float r0 = fmaxf(di * (sum.x + self.x) + b[f0 + 0], 0.f);
    float r1 = fmaxf(di * (sum.y + self.y) + b[f0 + 1], 0.f);
    float r2 = fmaxf(di * (sum.z + self.z) + b[f0 + 2], 0.f);
    float r3 = fmaxf(di * (sum.w + self.w) + b[f0 + 3], 0.f);
    float* op = &out[(size_t)node * ostride + col0 + f0];
    if (OV) {
        *(float4*)op = make_float4(r0, r1, r2, r3);
    } else {
        op[0] = r0; op[1] = r1; op[2] = r2; op[3] = r3;
    }
}

// ---------------- GCN dense: out[r,c] = dinv[r] * sum_k x[r,k]*W[k,c] ----------------
// BM=64 rows/block, 256 threads. x staged row-major in LDS; W read from global (L1-hot).
template<int K, int OC>
__global__ __launch_bounds__(256) void gemm_gcn(
    const float* __restrict__ x, const float* __restrict__ W,
    const float* __restrict__ dinv, float* __restrict__ outp, int n) {
    constexpr int CG = OC / 8;        // col groups
    constexpr int RG = 256 / CG;      // row groups
    constexpr int ROWS = 64 / RG;     // rows per thread
    __shared__ float xL[64][K + 4];

    const int tid = threadIdx.x;
    const int cg = tid % CG, rg = tid / CG;
    const int c0 = cg * 8, r0 = rg * ROWS;
    const int row0 = blockIdx.x * 64;

    // stage x tile (64 x K) via float4
#pragma unroll
    for (int i = 0; i < K / 16; ++i) {
        int e = tid + i * 256;
        int r = e / (K / 4), q = e % (K / 4);
        float4 v = make_float4(0.f, 0.f, 0.f, 0.f);
        if (row0 + r < n) v = *(const float4*)&x[(size_t)(row0 + r) * K + q * 4];
        *(float4*)&xL[r][q * 4] = v;
    }
    __syncthreads();

    float acc[ROWS][8];
#pragma unroll
    for (int r = 0; r < ROWS; ++r)
#pragma unroll
        for (int c = 0; c < 8; ++c) acc[r][c] = 0.f;

#pragma unroll 8
    for (int k = 0; k < K; ++k) {
        float4 w0 = *(const float4*)&W[(size_t)k * OC + c0];
        float4 w1 = *(const float4*)&W[(size_t)k * OC + c0 + 4];
        float wv[8] = {w0.x, w0.y, w0.z, w0.w, w1.x, w1.y, w1.z, w1.w};
        float xv[ROWS];
#pragma unroll
        for (int r = 0; r < ROWS; ++r) xv[r] = xL[r0 + r][k];
#pragma unroll
        for (int r = 0; r < ROWS; ++r)
#pragma unroll
            for (int c = 0; c < 8; ++c) acc[r][c] = fmaf(xv[r], wv[c], acc[r][c]);
    }

#pragma unroll
    for (int r = 0; r < ROWS; ++r) {
        int gr = row0 + r0 + r;
        if (gr >= n) continue;
        float di = dinv[gr];
        float* op = &outp[(size_t)gr * OC + c0];
        *(float4*)op = make_float4(acc[r][0] * di, acc[r][1] * di, acc[r][2] * di, acc[r][3] * di);
        *(float4*)(op + 4) = make_float4(acc[r][4] * di, acc[r][5] * di, acc[r][6] * di, acc[r][7] * di);
    }
}

// ---------------- fused decoder: emb -> head + 3 dense layers ----------------
// Per block: 64 rows. emb read from out[:,0:32); writes out[:,32:42) and out[:,42:170).
// h1, h2 live only in LDS. Weights read from global in k-loop (L1-resident).
__global__ __launch_bounds__(256) void decoder_fused(
    const float* obuf,
    const float* __restrict__ Wp, const float* __restrict__ bp,
    const float* __restrict__ Wd1, const float* __restrict__ bd1,
    const float* __restrict__ Wd2, const float* __restrict__ bd2,
    const float* __restrict__ Wd3, const float* __restrict__ bd3,
    float* out, int n) {
    __shared__ float xA[64][36];    // emb tile (64x32)
    __shared__ float xB[64][132];   // h1
    __shared__ float xC[64][132];   // h2

    const int tid = threadIdx.x;
    const int row0 = blockIdx.x * 64;
    const int cg = tid & 15, rg = tid >> 4;   // 16 col-groups x 16 row-groups
    const int c0 = cg * 8, r0 = rg * 4;

    // ---- load emb tile as float2 (rows of out are only 8B aligned) ----
#pragma unroll
    for (int i = 0; i < 4; ++i) {
        int e = tid + i * 256;
        int r = e >> 4, q = e & 15;
        float2 v = make_float2(0.f, 0.f);
        if (row0 + r < n) v = *(const float2*)&obuf[(size_t)(row0 + r) * 170 + q * 2];
        xA[r][q * 2] = v.x; xA[r][q * 2 + 1] = v.y;
    }
    __syncthreads();

    // ---- head: out[:,32:42) = emb @ Wp + bp ----
    for (int e = tid; e < 640; e += 256) {
        int r = e / 10, c = e % 10;
        if (row0 + r < n) {
            float acc = bp[c];
#pragma unroll
            for (int k = 0; k < 32; ++k) acc = fmaf(xA[r][k], Wp[k * 10 + c], acc);
            out[(size_t)(row0 + r) * 170 + 32 + c] = acc;
        }
    }

    // ---- stage 1: h1 = relu(emb @ Wd1 + bd1), K=32 -> xB ----
    {
        float acc[4][8];
#pragma unroll
        for (int r = 0; r < 4; ++r)
#pragma unroll
            for (int c = 0; c < 8; ++c) acc[r][c] = bd1[c0 + c];
#pragma unroll 8
        for (int k = 0; k < 32; ++k) {
            float4 w0 = *(const float4*)&Wd1[k * 128 + c0];
            float4 w1 = *(const float4*)&Wd1[k * 128 + c0 + 4];
            float wv[8] = {w0.x, w0.y, w0.z, w0.w, w1.x, w1.y, w1.z, w1.w};
            float xv[4] = {xA[r0][k], xA[r0 + 1][k], xA[r0 + 2][k], xA[r0 + 3][k]};
#pragma unroll
            for (int r = 0; r < 4; ++r)
#pragma unroll
                for (int c = 0; c < 8; ++c) acc[r][c] = fmaf(xv[r], wv[c], acc[r][c]);
        }
#pragma unroll
        for (int r = 0; r < 4; ++r) {
#pragma unroll
            for (int c = 0; c < 8; ++c) xB[r0 + r][c0 + c] = fmaxf(acc[r][c], 0.f);
        }
    }
    __syncthreads();

    // ---- stage 2: h2 = relu(h1 @ Wd2 + bd2), K=128 -> xC ----
    {
        float acc[4][8];
#pragma unroll
        for (int r = 0; r < 4; ++r)
#pragma unroll
            for (int c = 0; c < 8; ++c) acc[r][c] = bd2[c0 + c];
#pragma unroll 8
        for (int k = 0; k < 128; ++k) {
            float4 w0 = *(const float4*)&Wd2[k * 128 + c0];
            float4 w1 = *(const float4*)&Wd2[k * 128 + c0 + 4];
            float wv[8] = {w0.x, w0.y, w0.z, w0.w, w1.x, w1.y, w1.z, w1.w};
            float xv[4] = {xB[r0][k], xB[r0 + 1][k], xB[r0 + 2][k], xB[r0 + 3][k]};
#pragma unroll
            for (int r = 0; r < 4; ++r)
#pragma unroll
                for (int c = 0; c < 8; ++c) acc[r][c] = fmaf(xv[r], wv[c], acc[r][c]);
        }
#pragma unroll
        for (int r = 0; r < 4; ++r) {
#pragma unroll
            for (int c = 0; c < 8; ++c) xC[r0 + r][c0 + c] = fmaxf(acc[r][c], 0.f);
        }
    }
    __syncthreads();

    // ---- stage 3: dec = softplus(h2 @ Wd3 + bd3) -> out[:,42:170) ----
    {
        float acc[4][8];
#pragma unroll
        for (int r = 0; r < 4; ++r)
#pragma unroll
            for (int c = 0; c < 8; ++c) acc[r][c] = bd3[c0 + c];
#pragma unroll 8
        for (int k = 0; k < 128; ++k) {
            float4 w0 = *(const float4*)&Wd3[k * 128 + c0];
            float4 w1 = *(const float4*)&Wd3[k * 128 + c0 + 4];
            float wv[8] = {w0.x, w0.y, w0.z, w0.w, w1.x, w1.y, w1.z, w1.w};
            float xv[4] = {xC[r0][k], xC[r0 + 1][k], xC[r0 + 2][k], xC[r0 + 3][k]};
#pragma unroll
            for (int r = 0; r < 4; ++r)
#pragma unroll
                for (int c = 0; c < 8; ++c) acc[r][c] = fmaf(xv[r], wv[c], acc[r][c]);
        }
#pragma unroll
        for (int r = 0; r < 4; ++r) {
            int gr = row0 + r0 + r;
            if (gr >= n) continue;
            float* op = &out[(size_t)gr * 170 + 42 + c0];
#pragma unroll
            for (int c = 0; c < 8; c += 2) {
                float v0 = acc[r][c], v1 = acc[r][c + 1];
                v0 = fmaxf(v0, 0.f) + log1pf(expf(-fabsf(v0)));
                v1 = fmaxf(v1, 0.f) + log1pf(expf(-fabsf(v1)));
                *(float2*)(op + c) = make_float2(v0, v1);
            }
        }
    }
}

// ---------------- launch ----------------

extern "C" void kernel_launch(void* const* d_in, const int* in_sizes, int n_in,
                              void* d_out, int out_size, void* d_ws, size_t ws_size,
                              hipStream_t stream) {
    const float* raw_x = (const float*)d_in[0];
    const int*   ei    = (const int*)d_in[1];
    const float* W1 = (const float*)d_in[2];  const float* b1 = (const float*)d_in[3];
    const float* W2 = (const float*)d_in[4];  const float* b2 = (const float*)d_in[5];
    const float* Wp = (const float*)d_in[6];  const float* bp = (const float*)d_in[7];
    const float* Wd1 = (const float*)d_in[8]; const float* bd1 = (const float*)d_in[9];
    const float* Wd2 = (const float*)d_in[10]; const float* bd2 = (const float*)d_in[11];
    const float* Wd3 = (const float*)d_in[12]; const float* bd3 = (const float*)d_in[13];

    const int n = in_sizes[0] / 128;   // 50000
    const int E = in_sizes[1] / 2;     // 800000
    const int* row = ei;        // source
    const int* col = ei + E;    // target

    float* out = (float*)d_out;

    // workspace layout
    char* ws = (char*)d_ws;
    int*   deg    = (int*)ws;                        ws += (size_t)n * 4;
    float* dinv   = (float*)ws;                      ws += (size_t)n * 4;
    int*   rowptr = (int*)ws;                        ws += (size_t)(n + 4) * 4;
    int*   cursor = (int*)ws;                        ws += (size_t)n * 4;
    int*   bsum   = (int*)ws;                        ws += 64 * 4;
    int*   bpre   = (int*)ws;                        ws += 64 * 4;
    int*   csrc   = (int*)ws;                        ws += (size_t)E * 4;
    float* hs1    = (float*)ws;                      // [n,64]
    float* x1     = hs1 + (size_t)n * 64;            // [n,64]
    float* hs2    = x1 + (size_t)n * 64;             // [n,32]

    const int BS = 256;
    auto blocks = [](long long work, int bs) { return (unsigned)((work + bs - 1) / bs); };
    const int nb = (n + 1023) / 1024;                // scan blocks (49)

    // ---- graph structure (CSR by target) ----
    hipMemsetAsync(deg, 0, (size_t)n * 4, stream);
    deg_kernel<<<blocks(E, BS), BS, 0, stream>>>(col, deg, E);
    dinv_kernel<<<blocks(n, BS), BS, 0, stream>>>(deg, dinv, n);
    scan_phase1<<<nb, 256, 0, stream>>>(deg, bsum, n);
    scan_phase2<<<1, 64, 0, stream>>>(bsum, bpre, nb, rowptr, n, E);
    scan_phase3<<<nb, 256, 0, stream>>>(deg, bpre, rowptr, cursor, n);
    fill_kernel<<<blocks(E, BS), BS, 0, stream>>>(row, col, cursor, csrc, E);

    // ---- GCN layer 1: raw_x[128] -> 64 ----
    gemm_gcn<128, 64><<<blocks(n, 64), 256, 0, stream>>>(raw_x, W1, dinv, hs1, n);
    agg_finalize<64, true><<<blocks((long long)n * 16, BS), BS, 0, stream>>>(
        rowptr, csrc, hs1, dinv, b1, x1, n, 64, 0);

    // ---- GCN layer 2: x1[64] -> 32 ----
    gemm_gcn<64, 32><<<blocks(n, 64), 256, 0, stream>>>(x1, W2, dinv, hs2, n);
    agg_finalize<32, false><<<blocks((long long)n * 8, BS), BS, 0, stream>>>(
        rowptr, csrc, hs2, dinv, b2, out, n, 170, 0);   // emb -> out[:,0:32)

    // ---- fused decoder: head + 3 dense layers ----
    decoder_fused<<<blocks(n, 64), 256, 0, stream>>>(
        out, Wp, bp, Wd1, bd1, Wd2, bd2, Wd3, bd3, out, n);
}